// Round 1
// baseline (921.688 us; speedup 1.0000x reference)
//
#include <hip/hip_runtime.h>
#include <cstdint>
#include <cstddef>

#define N_NODES_C 100000
#define N_EDGES_C 1600000
#define N_VOCAB_C 50000
#define DIM_C 128
#define NEG_SLOPE_C 0.2f

// ---------------------------------------------------------------------------
// GEMM: XW = X @ W   (X: [n,128] f32, W: [128,128] f32, row-major)
// Block: 256 threads, 64 rows per block. Thread computes 8 rows x 4 cols.
// x-tile staged in LDS (32 KB); W streamed from global (L1/L2-resident, 64 KB).
// ---------------------------------------------------------------------------
__global__ __launch_bounds__(256) void gemm_xw(const float* __restrict__ X,
                                               const float* __restrict__ W,
                                               float* __restrict__ XW, int n) {
    __shared__ float xs[64][128];   // 32 KB
    const int row0 = blockIdx.x * 64;

    // Cooperative load of x tile: 64 rows * 32 float4 = 2048 float4
    {
        const float4* Xv = (const float4*)X;
        float4* xsv = (float4*)&xs[0][0];
        for (int i = threadIdx.x; i < 2048; i += 256) {
            int r = row0 + (i >> 5);
            float4 v = make_float4(0.f, 0.f, 0.f, 0.f);
            if (r < n) v = Xv[(size_t)r * 32 + (i & 31)];
            xsv[i] = v;
        }
    }
    __syncthreads();

    const int c0 = (threadIdx.x & 31) * 4;   // output col group
    const int r0 = (threadIdx.x >> 5) * 8;   // row group within tile

    float acc[8][4];
#pragma unroll
    for (int i = 0; i < 8; i++)
#pragma unroll
        for (int j = 0; j < 4; j++) acc[i][j] = 0.f;

    const float4* W4 = (const float4*)W;
    for (int k = 0; k < 128; k += 4) {
        float4 w0 = W4[(k + 0) * 32 + (c0 >> 2)];
        float4 w1 = W4[(k + 1) * 32 + (c0 >> 2)];
        float4 w2 = W4[(k + 2) * 32 + (c0 >> 2)];
        float4 w3 = W4[(k + 3) * 32 + (c0 >> 2)];
#pragma unroll
        for (int i = 0; i < 8; i++) {
            float4 xv = *(const float4*)&xs[r0 + i][k];
            acc[i][0] += xv.x * w0.x + xv.y * w1.x + xv.z * w2.x + xv.w * w3.x;
            acc[i][1] += xv.x * w0.y + xv.y * w1.y + xv.z * w2.y + xv.w * w3.y;
            acc[i][2] += xv.x * w0.z + xv.y * w1.z + xv.z * w2.z + xv.w * w3.z;
            acc[i][3] += xv.x * w0.w + xv.y * w1.w + xv.z * w2.w + xv.w * w3.w;
        }
    }

#pragma unroll
    for (int i = 0; i < 8; i++) {
        int r = row0 + r0 + i;
        if (r < n) {
            *(float4*)(XW + (size_t)r * 128 + c0) =
                make_float4(acc[i][0], acc[i][1], acc[i][2], acc[i][3]);
        }
    }
}

// ---------------------------------------------------------------------------
// Per-node attention scalars: s_src[v] = xw[v].a_src ; s_dst[v] = xw[v].a_dst
// One wave per node; lane l covers dims [2l, 2l+1].
// ---------------------------------------------------------------------------
__global__ __launch_bounds__(256) void node_scalars(const float* __restrict__ XW,
                                                    const float* __restrict__ a_src,
                                                    const float* __restrict__ a_dst,
                                                    float* __restrict__ s_src,
                                                    float* __restrict__ s_dst, int n) {
    int wid = (blockIdx.x * 256 + threadIdx.x) >> 6;
    int lane = threadIdx.x & 63;
    if (wid >= n) return;
    float2 x2 = *(const float2*)(XW + (size_t)wid * 128 + lane * 2);
    float2 as = *(const float2*)(a_src + lane * 2);
    float2 ad = *(const float2*)(a_dst + lane * 2);
    float ps = x2.x * as.x + x2.y * as.y;
    float pd = x2.x * ad.x + x2.y * ad.y;
#pragma unroll
    for (int off = 32; off; off >>= 1) {
        ps += __shfl_xor(ps, off);
        pd += __shfl_xor(pd, off);
    }
    if (lane == 0) { s_src[wid] = ps; s_dst[wid] = pd; }
}

// ---------------------------------------------------------------------------
// CSR build helpers
// ---------------------------------------------------------------------------
__global__ void zero2_kernel(int* __restrict__ a, int* __restrict__ b, int n) {
    int i = blockIdx.x * 256 + threadIdx.x;
    if (i < n) { a[i] = 0; b[i] = 0; }
}

__global__ void edge_count(const int* __restrict__ dst, int* __restrict__ cnt, int e) {
    int i = blockIdx.x * 256 + threadIdx.x;
    if (i < e) atomicAdd(&cnt[dst[i]], 1);
}

// scan1: per-block (1024 elems) exclusive scan of cnt -> row_start; block total -> bsum
__global__ __launch_bounds__(256) void scan1(const int* __restrict__ cnt,
                                             int* __restrict__ row_start,
                                             int* __restrict__ bsum, int n) {
    __shared__ int ls[256];
    int t = threadIdx.x;
    int base = blockIdx.x * 1024 + t * 4;
    int v0 = (base + 0 < n) ? cnt[base + 0] : 0;
    int v1 = (base + 1 < n) ? cnt[base + 1] : 0;
    int v2 = (base + 2 < n) ? cnt[base + 2] : 0;
    int v3 = (base + 3 < n) ? cnt[base + 3] : 0;
    int tsum = v0 + v1 + v2 + v3;
    ls[t] = tsum;
    __syncthreads();
    for (int off = 1; off < 256; off <<= 1) {
        int x = (t >= off) ? ls[t - off] : 0;
        __syncthreads();
        ls[t] += x;
        __syncthreads();
    }
    int excl = ls[t] - tsum;
    if (t == 255) bsum[blockIdx.x] = ls[255];
    if (base + 0 < n) row_start[base + 0] = excl;
    if (base + 1 < n) row_start[base + 1] = excl + v0;
    if (base + 2 < n) row_start[base + 2] = excl + v0 + v1;
    if (base + 3 < n) row_start[base + 3] = excl + v0 + v1 + v2;
}

// scan2: single block exclusive scan of nb (<=256) block sums -> bbase
__global__ __launch_bounds__(256) void scan2(const int* __restrict__ bsum,
                                             int* __restrict__ bbase, int nb) {
    __shared__ int ls[256];
    int t = threadIdx.x;
    int v = (t < nb) ? bsum[t] : 0;
    ls[t] = v;
    __syncthreads();
    for (int off = 1; off < 256; off <<= 1) {
        int x = (t >= off) ? ls[t - off] : 0;
        __syncthreads();
        ls[t] += x;
        __syncthreads();
    }
    if (t < nb) bbase[t] = ls[t] - v;
}

// scan3: add block bases; write row_start[n] = E
__global__ void scan3(int* __restrict__ row_start, const int* __restrict__ bbase,
                      int n, int e) {
    int i = blockIdx.x * 256 + threadIdx.x;
    if (i < n) row_start[i] += bbase[i >> 10];
    if (i == 0) row_start[n] = e;
}

__global__ void edge_fill(const int* __restrict__ src, const int* __restrict__ dst,
                          const int* __restrict__ row_start, int* __restrict__ fills,
                          int* __restrict__ col_src, int e) {
    int i = blockIdx.x * 256 + threadIdx.x;
    if (i < e) {
        int d = dst[i];
        int pos = atomicAdd(&fills[d], 1);
        col_src[row_start[d] + pos] = src[i];
    }
}

// ---------------------------------------------------------------------------
// GAT aggregation: one wave per destination node.
// out[v] = (sum_{u in N(v) ∪ {v}} exp(lrelu(s_src[u]+s_dst[v])) * xw[u]) / psum + bias
// No max-subtraction needed: logits are O(1) here, exp(m) cancels exactly in alpha.
// ---------------------------------------------------------------------------
__global__ __launch_bounds__(256) void gat_agg(const float* __restrict__ XW,
                                               const int* __restrict__ row_start,
                                               const int* __restrict__ col_src,
                                               const float* __restrict__ s_src,
                                               const float* __restrict__ s_dst,
                                               const float* __restrict__ bias,
                                               float* __restrict__ OUT, int n) {
    int v = (blockIdx.x * 256 + threadIdx.x) >> 6;
    int lane = threadIdx.x & 63;
    if (v >= n) return;

    float sdv = s_dst[v];

    // self-loop (appended unconditionally by reference)
    float e = s_src[v] + sdv;
    e = (e > 0.f) ? e : NEG_SLOPE_C * e;
    float p = __expf(e);
    float2 xv = *(const float2*)(XW + (size_t)v * 128 + lane * 2);
    float accx = p * xv.x;
    float accy = p * xv.y;
    float psum = p;

    int beg = row_start[v];
    int end = row_start[v + 1];
    for (int j = beg; j < end; ++j) {
        int u = col_src[j];
        float ee = s_src[u] + sdv;
        ee = (ee > 0.f) ? ee : NEG_SLOPE_C * ee;
        float pp = __expf(ee);
        float2 xu = *(const float2*)(XW + (size_t)u * 128 + lane * 2);
        accx += pp * xu.x;
        accy += pp * xu.y;
        psum += pp;
    }

    float inv = 1.0f / psum;
    float2 b2 = *(const float2*)(bias + lane * 2);
    float2 o;
    o.x = accx * inv + b2.x;
    o.y = accy * inv + b2.y;
    *(float2*)(OUT + (size_t)v * 128 + lane * 2) = o;
}

// ---------------------------------------------------------------------------
// Final gather: out[i] = H[idx[i]]
// ---------------------------------------------------------------------------
__global__ __launch_bounds__(256) void gather_rows(const float* __restrict__ H,
                                                   const int* __restrict__ idx,
                                                   float* __restrict__ out, int n) {
    int wid = (blockIdx.x * 256 + threadIdx.x) >> 6;
    int lane = threadIdx.x & 63;
    if (wid >= n) return;
    int v = idx[wid];
    float2 x2 = *(const float2*)(H + (size_t)v * 128 + lane * 2);
    *(float2*)(out + (size_t)wid * 128 + lane * 2) = x2;
}

// ---------------------------------------------------------------------------
// Launcher
// ---------------------------------------------------------------------------
extern "C" void kernel_launch(void* const* d_in, const int* in_sizes, int n_in,
                              void* d_out, int out_size, void* d_ws, size_t ws_size,
                              hipStream_t stream) {
    const float* emb   = (const float*)d_in[0];
    const float* W     = (const float*)d_in[1];
    const float* a_src = (const float*)d_in[2];
    const float* a_dst = (const float*)d_in[3];
    const float* bias  = (const float*)d_in[4];
    const int*   e1    = (const int*)d_in[5];   // [2, E]: src row then dst row
    const int*   e2    = (const int*)d_in[6];
    const int*   idx   = (const int*)d_in[7];
    float* out = (float*)d_out;

    const int n = N_NODES_C;
    const int E = N_EDGES_C;

    // Workspace carve-up (~111 MB total; all buffers fully rewritten every call)
    char* ws = (char*)d_ws;
    auto alloc = [&](size_t bytes) {
        char* p = ws;
        ws += (bytes + 511) & ~(size_t)511;
        return p;
    };
    float* A        = (float*)alloc((size_t)n * DIM_C * 4);   // xw of current layer
    float* B        = (float*)alloc((size_t)n * DIM_C * 4);   // layer output
    float* s_src    = (float*)alloc((size_t)n * 4);
    float* s_dst    = (float*)alloc((size_t)n * 4);
    int*   cnt      = (int*)  alloc((size_t)n * 4);
    int*   fills    = (int*)  alloc((size_t)n * 4);
    int*   rowst    = (int*)  alloc((size_t)(n + 1) * 4);
    int*   bsum     = (int*)  alloc(512);
    int*   bbase    = (int*)  alloc(512);
    int*   col_src  = (int*)  alloc((size_t)E * 4);
    (void)ws_size; (void)in_sizes; (void)n_in; (void)out_size;

    const int gemm_blocks  = (n + 63) / 64;
    const int wave_blocks  = (n * 64 + 255) / 256;      // one wave per node
    const int node_blocks  = (n + 255) / 256;
    const int edge_blocks  = (E + 255) / 256;
    const int scan_blocks  = (n + 1023) / 1024;         // 98
    const int gath_blocks  = (N_VOCAB_C * 64 + 255) / 256;

    auto run_layer = [&](const float* x_in, const int* edges) {
        const int* esrc = edges;
        const int* edst = edges + E;
        // xw = x @ W, then per-node scalars
        gemm_xw<<<gemm_blocks, 256, 0, stream>>>(x_in, W, A, n);
        node_scalars<<<wave_blocks, 256, 0, stream>>>(A, a_src, a_dst, s_src, s_dst, n);
        // CSR by dst
        zero2_kernel<<<node_blocks, 256, 0, stream>>>(cnt, fills, n);
        edge_count<<<edge_blocks, 256, 0, stream>>>(edst, cnt, E);
        scan1<<<scan_blocks, 256, 0, stream>>>(cnt, rowst, bsum, n);
        scan2<<<1, 256, 0, stream>>>(bsum, bbase, scan_blocks);
        scan3<<<node_blocks, 256, 0, stream>>>(rowst, bbase, n, E);
        edge_fill<<<edge_blocks, 256, 0, stream>>>(esrc, edst, rowst, fills, col_src, E);
        // aggregate + bias
        gat_agg<<<wave_blocks, 256, 0, stream>>>(A, rowst, col_src, s_src, s_dst,
                                                 bias, B, n);
    };

    run_layer(emb, e1);   // B = h1
    run_layer(B, e2);     // A = h1@W (reads B, writes A), then B = h2
    gather_rows<<<gath_blocks, 256, 0, stream>>>(B, idx, out, N_VOCAB_C);
}

// Round 2
// 791.815 us; speedup vs baseline: 1.1640x; 1.1640x over previous
//
#include <hip/hip_runtime.h>
#include <cstdint>
#include <cstddef>

#define N_NODES_C 100000
#define N_EDGES_C 1600000
#define N_VOCAB_C 50000
#define DIM_C 128
#define NEG_SLOPE_C 0.2f

// ---------------------------------------------------------------------------
// GEMM + fused per-node attention scalars + cnt/fills zeroing.
// XW = X @ W   (X: [n,128] f32, W: [128,128] f32, row-major)
// Block: 256 threads, 64 rows per block. Thread computes 8 rows x 4 cols.
// Epilogue: s_src[r] = xw[r].a_src, s_dst[r] = xw[r].a_dst via half-wave reduce.
// Also zeroes cnt[] and fills[] for the CSR build (saves a dispatch).
// ---------------------------------------------------------------------------
__global__ __launch_bounds__(256) void gemm_xw(const float* __restrict__ X,
                                               const float* __restrict__ W,
                                               const float* __restrict__ a_src,
                                               const float* __restrict__ a_dst,
                                               float* __restrict__ XW,
                                               float* __restrict__ s_src,
                                               float* __restrict__ s_dst,
                                               int* __restrict__ cnt,
                                               int* __restrict__ fills, int n) {
    __shared__ float xs[64][128];   // 32 KB
    const int row0 = blockIdx.x * 64;

    // zero CSR counters for this block's row range
    if (threadIdx.x < 64) {
        int r = row0 + threadIdx.x;
        if (r < n) { cnt[r] = 0; fills[r] = 0; }
    }

    // Cooperative load of x tile: 64 rows * 32 float4 = 2048 float4
    {
        const float4* Xv = (const float4*)X;
        float4* xsv = (float4*)&xs[0][0];
        for (int i = threadIdx.x; i < 2048; i += 256) {
            int r = row0 + (i >> 5);
            float4 v = make_float4(0.f, 0.f, 0.f, 0.f);
            if (r < n) v = Xv[(size_t)r * 32 + (i & 31)];
            xsv[i] = v;
        }
    }
    __syncthreads();

    const int cg = threadIdx.x & 31;         // col group id
    const int c0 = cg * 4;                   // output col base
    const int r0 = (threadIdx.x >> 5) * 8;   // row group within tile

    float acc[8][4];
#pragma unroll
    for (int i = 0; i < 8; i++)
#pragma unroll
        for (int j = 0; j < 4; j++) acc[i][j] = 0.f;

    const float4* W4 = (const float4*)W;
    for (int k = 0; k < 128; k += 4) {
        float4 w0 = W4[(k + 0) * 32 + cg];
        float4 w1 = W4[(k + 1) * 32 + cg];
        float4 w2 = W4[(k + 2) * 32 + cg];
        float4 w3 = W4[(k + 3) * 32 + cg];
#pragma unroll
        for (int i = 0; i < 8; i++) {
            float4 xv = *(const float4*)&xs[r0 + i][k];
            acc[i][0] += xv.x * w0.x + xv.y * w1.x + xv.z * w2.x + xv.w * w3.x;
            acc[i][1] += xv.x * w0.y + xv.y * w1.y + xv.z * w2.y + xv.w * w3.y;
            acc[i][2] += xv.x * w0.z + xv.y * w1.z + xv.z * w2.z + xv.w * w3.z;
            acc[i][3] += xv.x * w0.w + xv.y * w1.w + xv.z * w2.w + xv.w * w3.w;
        }
    }

    // store XW
#pragma unroll
    for (int i = 0; i < 8; i++) {
        int r = row0 + r0 + i;
        if (r < n) {
            *(float4*)(XW + (size_t)r * 128 + c0) =
                make_float4(acc[i][0], acc[i][1], acc[i][2], acc[i][3]);
        }
    }

    // fused attention scalars: per row, dot(acc_row, a_src/a_dst) reduced
    // across the 32 threads (half-wave) covering that row.
    float4 asv = *(const float4*)(a_src + c0);
    float4 adv = *(const float4*)(a_dst + c0);
#pragma unroll
    for (int i = 0; i < 8; i++) {
        float ps = acc[i][0] * asv.x + acc[i][1] * asv.y +
                   acc[i][2] * asv.z + acc[i][3] * asv.w;
        float pd = acc[i][0] * adv.x + acc[i][1] * adv.y +
                   acc[i][2] * adv.z + acc[i][3] * adv.w;
#pragma unroll
        for (int off = 16; off; off >>= 1) {
            ps += __shfl_xor(ps, off);
            pd += __shfl_xor(pd, off);
        }
        int r = row0 + r0 + i;
        if (cg == 0 && r < n) { s_src[r] = ps; s_dst[r] = pd; }
    }
}

// ---------------------------------------------------------------------------
// CSR build helpers
// ---------------------------------------------------------------------------
__global__ void edge_count(const int* __restrict__ dst, int* __restrict__ cnt, int e) {
    int i = blockIdx.x * 256 + threadIdx.x;
    if (i < e) atomicAdd(&cnt[dst[i]], 1);
}

// scan1: per-block (1024 elems) exclusive scan of cnt -> row_start; block total -> bsum
__global__ __launch_bounds__(256) void scan1(const int* __restrict__ cnt,
                                             int* __restrict__ row_start,
                                             int* __restrict__ bsum, int n) {
    __shared__ int ls[256];
    int t = threadIdx.x;
    int base = blockIdx.x * 1024 + t * 4;
    int v0 = (base + 0 < n) ? cnt[base + 0] : 0;
    int v1 = (base + 1 < n) ? cnt[base + 1] : 0;
    int v2 = (base + 2 < n) ? cnt[base + 2] : 0;
    int v3 = (base + 3 < n) ? cnt[base + 3] : 0;
    int tsum = v0 + v1 + v2 + v3;
    ls[t] = tsum;
    __syncthreads();
    for (int off = 1; off < 256; off <<= 1) {
        int x = (t >= off) ? ls[t - off] : 0;
        __syncthreads();
        ls[t] += x;
        __syncthreads();
    }
    int excl = ls[t] - tsum;
    if (t == 255) bsum[blockIdx.x] = ls[255];
    if (base + 0 < n) row_start[base + 0] = excl;
    if (base + 1 < n) row_start[base + 1] = excl + v0;
    if (base + 2 < n) row_start[base + 2] = excl + v0 + v1;
    if (base + 3 < n) row_start[base + 3] = excl + v0 + v1 + v2;
}

// scan2: single block exclusive scan of nb (<=256) block sums -> bbase
__global__ __launch_bounds__(256) void scan2(const int* __restrict__ bsum,
                                             int* __restrict__ bbase, int nb) {
    __shared__ int ls[256];
    int t = threadIdx.x;
    int v = (t < nb) ? bsum[t] : 0;
    ls[t] = v;
    __syncthreads();
    for (int off = 1; off < 256; off <<= 1) {
        int x = (t >= off) ? ls[t - off] : 0;
        __syncthreads();
        ls[t] += x;
        __syncthreads();
    }
    if (t < nb) bbase[t] = ls[t] - v;
}

// scan3: add block bases; write row_start[n] = E
__global__ void scan3(int* __restrict__ row_start, const int* __restrict__ bbase,
                      int n, int e) {
    int i = blockIdx.x * 256 + threadIdx.x;
    if (i < n) row_start[i] += bbase[i >> 10];
    if (i == 0) row_start[n] = e;
}

__global__ void edge_fill(const int* __restrict__ src, const int* __restrict__ dst,
                          const int* __restrict__ row_start, int* __restrict__ fills,
                          int* __restrict__ col_src, int e) {
    int i = blockIdx.x * 256 + threadIdx.x;
    if (i < e) {
        int d = dst[i];
        int pos = atomicAdd(&fills[d], 1);
        col_src[row_start[d] + pos] = src[i];
    }
}

// ---------------------------------------------------------------------------
// GAT aggregation: one wave per destination node, latency-optimized.
//  - col_src loaded lane-coalesced, 64 edges per chunk
//  - s_src gathered per-lane; leaky-relu+exp computed wave-parallel (once/edge)
//  - psum accumulated as per-lane partials, single shfl-reduce at the end
//  - row gathers unrolled x8 -> 8 outstanding 512B loads per wave
// ---------------------------------------------------------------------------
__global__ __launch_bounds__(256) void gat_agg(const float* __restrict__ XW,
                                               const int* __restrict__ row_start,
                                               const int* __restrict__ col_src,
                                               const float* __restrict__ s_src,
                                               const float* __restrict__ s_dst,
                                               const float* __restrict__ bias,
                                               float* __restrict__ OUT, int n) {
    int v = (blockIdx.x * 256 + threadIdx.x) >> 6;
    int lane = threadIdx.x & 63;
    if (v >= n) return;

    float sdv = s_dst[v];

    // self-loop (appended unconditionally by reference)
    float e0 = s_src[v] + sdv;
    e0 = (e0 > 0.f) ? e0 : NEG_SLOPE_C * e0;
    float p0 = __expf(e0);
    float2 xv = *(const float2*)(XW + (size_t)v * 128 + lane * 2);
    float accx = p0 * xv.x;
    float accy = p0 * xv.y;
    float psum_l = (lane == 0) ? p0 : 0.f;   // per-lane partial of the softmax denom

    const int beg = row_start[v];
    const int end = row_start[v + 1];

    for (int base = beg; base < end; base += 64) {
        int m = end - base;
        if (m > 64) m = 64;
        // lane-coalesced edge index + per-lane scalar gather + wave-parallel exp
        int u_l = (lane < m) ? col_src[base + lane] : v;
        float sl = s_src[u_l] + sdv;
        sl = (sl > 0.f) ? sl : NEG_SLOPE_C * sl;
        float pe = (lane < m) ? __expf(sl) : 0.f;
        psum_l += pe;

        int i = 0;
        for (; i + 8 <= m; i += 8) {
            int uu[8];
            float qq[8];
#pragma unroll
            for (int k = 0; k < 8; k++) {
                uu[k] = __shfl(u_l, i + k);
                qq[k] = __shfl(pe, i + k);
            }
            float2 xx[8];
#pragma unroll
            for (int k = 0; k < 8; k++)
                xx[k] = *(const float2*)(XW + (size_t)uu[k] * 128 + lane * 2);
#pragma unroll
            for (int k = 0; k < 8; k++) {
                accx = fmaf(qq[k], xx[k].x, accx);
                accy = fmaf(qq[k], xx[k].y, accy);
            }
        }
        for (; i < m; ++i) {
            int u = __shfl(u_l, i);
            float q = __shfl(pe, i);
            float2 xu = *(const float2*)(XW + (size_t)u * 128 + lane * 2);
            accx = fmaf(q, xu.x, accx);
            accy = fmaf(q, xu.y, accy);
        }
    }

    // wave-reduce the softmax denominator
    float ps = psum_l;
#pragma unroll
    for (int off = 32; off; off >>= 1) ps += __shfl_xor(ps, off);

    float inv = 1.0f / ps;
    float2 b2 = *(const float2*)(bias + lane * 2);
    float2 o;
    o.x = accx * inv + b2.x;
    o.y = accy * inv + b2.y;
    *(float2*)(OUT + (size_t)v * 128 + lane * 2) = o;
}

// ---------------------------------------------------------------------------
// Final gather: out[i] = H[idx[i]]  (32 lanes x float4 per row)
// ---------------------------------------------------------------------------
__global__ __launch_bounds__(256) void gather_rows(const float* __restrict__ H,
                                                   const int* __restrict__ idx,
                                                   float* __restrict__ out, int n) {
    int t = blockIdx.x * 256 + threadIdx.x;
    int r = t >> 5;
    int l = t & 31;
    if (r >= n) return;
    int v = idx[r];
    float4 x = *(const float4*)(H + (size_t)v * 128 + l * 4);
    *(float4*)(out + (size_t)r * 128 + l * 4) = x;
}

// ---------------------------------------------------------------------------
// Launcher
// ---------------------------------------------------------------------------
extern "C" void kernel_launch(void* const* d_in, const int* in_sizes, int n_in,
                              void* d_out, int out_size, void* d_ws, size_t ws_size,
                              hipStream_t stream) {
    const float* emb   = (const float*)d_in[0];
    const float* W     = (const float*)d_in[1];
    const float* a_src = (const float*)d_in[2];
    const float* a_dst = (const float*)d_in[3];
    const float* bias  = (const float*)d_in[4];
    const int*   e1    = (const int*)d_in[5];   // [2, E]: src row then dst row
    const int*   e2    = (const int*)d_in[6];
    const int*   idx   = (const int*)d_in[7];
    float* out = (float*)d_out;

    const int n = N_NODES_C;
    const int E = N_EDGES_C;

    // Workspace carve-up (~111 MB total; all buffers fully rewritten every call)
    char* ws = (char*)d_ws;
    auto alloc = [&](size_t bytes) {
        char* p = ws;
        ws += (bytes + 511) & ~(size_t)511;
        return p;
    };
    float* A        = (float*)alloc((size_t)n * DIM_C * 4);   // xw of current layer
    float* B        = (float*)alloc((size_t)n * DIM_C * 4);   // layer output
    float* s_src    = (float*)alloc((size_t)n * 4);
    float* s_dst    = (float*)alloc((size_t)n * 4);
    int*   cnt      = (int*)  alloc((size_t)n * 4);
    int*   fills    = (int*)  alloc((size_t)n * 4);
    int*   rowst    = (int*)  alloc((size_t)(n + 1) * 4);
    int*   bsum     = (int*)  alloc(512);
    int*   bbase    = (int*)  alloc(512);
    int*   col_src  = (int*)  alloc((size_t)E * 4);
    (void)ws_size; (void)in_sizes; (void)n_in; (void)out_size;

    const int gemm_blocks  = (n + 63) / 64;
    const int wave_blocks  = (n * 64 + 255) / 256;      // one wave per node
    const int node_blocks  = (n + 255) / 256;
    const int edge_blocks  = (E + 255) / 256;
    const int scan_blocks  = (n + 1023) / 1024;         // 98
    const int gath_blocks  = (N_VOCAB_C * 32 + 255) / 256;

    auto run_layer = [&](const float* x_in, const int* edges) {
        const int* esrc = edges;
        const int* edst = edges + E;
        // xw = x @ W (+ fused scalars + CSR counter zeroing)
        gemm_xw<<<gemm_blocks, 256, 0, stream>>>(x_in, W, a_src, a_dst,
                                                 A, s_src, s_dst, cnt, fills, n);
        // CSR by dst
        edge_count<<<edge_blocks, 256, 0, stream>>>(edst, cnt, E);
        scan1<<<scan_blocks, 256, 0, stream>>>(cnt, rowst, bsum, n);
        scan2<<<1, 256, 0, stream>>>(bsum, bbase, scan_blocks);
        scan3<<<node_blocks, 256, 0, stream>>>(rowst, bbase, n, E);
        edge_fill<<<edge_blocks, 256, 0, stream>>>(esrc, edst, rowst, fills, col_src, E);
        // aggregate + bias
        gat_agg<<<wave_blocks, 256, 0, stream>>>(A, rowst, col_src, s_src, s_dst,
                                                 bias, B, n);
    };

    run_layer(emb, e1);   // B = h1
    run_layer(B, e2);     // A = h1@W (reads B, writes A), then B = h2
    gather_rows<<<gath_blocks, 256, 0, stream>>>(B, idx, out, N_VOCAB_C);
}

// Round 3
// 753.923 us; speedup vs baseline: 1.2225x; 1.0503x over previous
//
#include <hip/hip_runtime.h>
#include <cstdint>
#include <cstddef>

#define N_NODES_C 100000
#define N_EDGES_C 1600000
#define N_VOCAB_C 50000
#define DIM_C 128
#define NEG_SLOPE_C 0.2f

// ---------------------------------------------------------------------------
// GEMM body (device fn): XW = X @ W for 64 rows starting at blk*64.
// 256 threads: thread computes 8 rows x 4 cols. Fused epilogue computes
// s_src[r] = xw[r].a_src, s_dst[r] = xw[r].a_dst via 32-thread shfl reduce.
// ---------------------------------------------------------------------------
__device__ __forceinline__ void gemm_body(const float* __restrict__ X,
                                          const float* __restrict__ W,
                                          const float* __restrict__ a_src,
                                          const float* __restrict__ a_dst,
                                          float* __restrict__ XW,
                                          float* __restrict__ s_src,
                                          float* __restrict__ s_dst,
                                          int n, int blk) {
    __shared__ float xs[64][128];   // 32 KB
    const int row0 = blk * 64;

    {
        const float4* Xv = (const float4*)X;
        float4* xsv = (float4*)&xs[0][0];
        for (int i = threadIdx.x; i < 2048; i += 256) {
            int r = row0 + (i >> 5);
            float4 v = make_float4(0.f, 0.f, 0.f, 0.f);
            if (r < n) v = Xv[(size_t)r * 32 + (i & 31)];
            xsv[i] = v;
        }
    }
    __syncthreads();

    const int cg = threadIdx.x & 31;         // col group id
    const int c0 = cg * 4;                   // output col base
    const int r0 = (threadIdx.x >> 5) * 8;   // row group within tile

    float acc[8][4];
#pragma unroll
    for (int i = 0; i < 8; i++)
#pragma unroll
        for (int j = 0; j < 4; j++) acc[i][j] = 0.f;

    const float4* W4 = (const float4*)W;
    for (int k = 0; k < 128; k += 4) {
        float4 w0 = W4[(k + 0) * 32 + cg];
        float4 w1 = W4[(k + 1) * 32 + cg];
        float4 w2 = W4[(k + 2) * 32 + cg];
        float4 w3 = W4[(k + 3) * 32 + cg];
#pragma unroll
        for (int i = 0; i < 8; i++) {
            float4 xv = *(const float4*)&xs[r0 + i][k];
            acc[i][0] += xv.x * w0.x + xv.y * w1.x + xv.z * w2.x + xv.w * w3.x;
            acc[i][1] += xv.x * w0.y + xv.y * w1.y + xv.z * w2.y + xv.w * w3.y;
            acc[i][2] += xv.x * w0.z + xv.y * w1.z + xv.z * w2.z + xv.w * w3.z;
            acc[i][3] += xv.x * w0.w + xv.y * w1.w + xv.z * w2.w + xv.w * w3.w;
        }
    }

#pragma unroll
    for (int i = 0; i < 8; i++) {
        int r = row0 + r0 + i;
        if (r < n) {
            *(float4*)(XW + (size_t)r * 128 + c0) =
                make_float4(acc[i][0], acc[i][1], acc[i][2], acc[i][3]);
        }
    }

    float4 asv = *(const float4*)(a_src + c0);
    float4 adv = *(const float4*)(a_dst + c0);
#pragma unroll
    for (int i = 0; i < 8; i++) {
        float ps = acc[i][0] * asv.x + acc[i][1] * asv.y +
                   acc[i][2] * asv.z + acc[i][3] * asv.w;
        float pd = acc[i][0] * adv.x + acc[i][1] * adv.y +
                   acc[i][2] * adv.z + acc[i][3] * adv.w;
#pragma unroll
        for (int off = 16; off; off >>= 1) {
            ps += __shfl_xor(ps, off);
            pd += __shfl_xor(pd, off);
        }
        int r = row0 + r0 + i;
        if (cg == 0 && r < n) { s_src[r] = ps; s_dst[r] = pd; }
    }
}

// ---------------------------------------------------------------------------
// Zero the CSR counter region (cnt1|fills1|cnt2|fills2, contiguous)
// ---------------------------------------------------------------------------
__global__ void zero_ws(int* __restrict__ z, int n4) {
    int i = blockIdx.x * 256 + threadIdx.x;
    if (i < n4) ((int4*)z)[i] = make_int4(0, 0, 0, 0);
}

// ---------------------------------------------------------------------------
// Fused: gemm layer1 + edge counting for BOTH edge sets (grid-partitioned).
// Counting (latency/atomic-bound) hides under the gemm (compute-bound).
// ---------------------------------------------------------------------------
__global__ __launch_bounds__(256) void fused_gemm_count(
        const float* __restrict__ X, const float* __restrict__ W,
        const float* __restrict__ a_src, const float* __restrict__ a_dst,
        float* __restrict__ XW, float* __restrict__ s_src, float* __restrict__ s_dst,
        const int* __restrict__ dst1, const int* __restrict__ dst2,
        int* __restrict__ cnt1, int* __restrict__ cnt2,
        int n, int E, int gemmBlocks, int countBlocks) {
    int b = blockIdx.x;
    if (b < gemmBlocks) {
        gemm_body(X, W, a_src, a_dst, XW, s_src, s_dst, n, b);
        return;
    }
    int cb = b - gemmBlocks;
    const int* dst; int* cnt;
    if (cb < countBlocks) { dst = dst1; cnt = cnt1; }
    else                  { dst = dst2; cnt = cnt2; cb -= countBlocks; }
    int i0 = (cb * 256 + threadIdx.x) * 4;
    if (i0 + 3 < E) {
        int4 d = *(const int4*)(dst + i0);
        atomicAdd(&cnt[d.x], 1);
        atomicAdd(&cnt[d.y], 1);
        atomicAdd(&cnt[d.z], 1);
        atomicAdd(&cnt[d.w], 1);
    } else {
        for (int k = 0; k < 4 && i0 + k < E; k++) atomicAdd(&cnt[dst[i0 + k]], 1);
    }
}

// Standalone gemm for layer 2
__global__ __launch_bounds__(256) void gemm_xw(const float* __restrict__ X,
                                               const float* __restrict__ W,
                                               const float* __restrict__ a_src,
                                               const float* __restrict__ a_dst,
                                               float* __restrict__ XW,
                                               float* __restrict__ s_src,
                                               float* __restrict__ s_dst, int n) {
    gemm_body(X, W, a_src, a_dst, XW, s_src, s_dst, n, blockIdx.x);
}

// ---------------------------------------------------------------------------
// Scans over BOTH counter arrays in one dispatch (grid-partitioned)
// ---------------------------------------------------------------------------
__device__ __forceinline__ void scan1_body(const int* __restrict__ cnt,
                                           int* __restrict__ row_start,
                                           int* __restrict__ bsum, int n, int blk) {
    __shared__ int ls[256];
    int t = threadIdx.x;
    int base = blk * 1024 + t * 4;
    int v0 = (base + 0 < n) ? cnt[base + 0] : 0;
    int v1 = (base + 1 < n) ? cnt[base + 1] : 0;
    int v2 = (base + 2 < n) ? cnt[base + 2] : 0;
    int v3 = (base + 3 < n) ? cnt[base + 3] : 0;
    int tsum = v0 + v1 + v2 + v3;
    ls[t] = tsum;
    __syncthreads();
    for (int off = 1; off < 256; off <<= 1) {
        int x = (t >= off) ? ls[t - off] : 0;
        __syncthreads();
        ls[t] += x;
        __syncthreads();
    }
    int excl = ls[t] - tsum;
    if (t == 255) bsum[blk] = ls[255];
    if (base + 0 < n) row_start[base + 0] = excl;
    if (base + 1 < n) row_start[base + 1] = excl + v0;
    if (base + 2 < n) row_start[base + 2] = excl + v0 + v1;
    if (base + 3 < n) row_start[base + 3] = excl + v0 + v1 + v2;
}

__global__ __launch_bounds__(256) void scan1_both(
        const int* __restrict__ cntA, int* __restrict__ rowA, int* __restrict__ bsumA,
        const int* __restrict__ cntB, int* __restrict__ rowB, int* __restrict__ bsumB,
        int n, int nbPerSet) {
    int b = blockIdx.x;
    if (b < nbPerSet) scan1_body(cntA, rowA, bsumA, n, b);
    else              scan1_body(cntB, rowB, bsumB, n, b - nbPerSet);
}

__device__ __forceinline__ void scan2_body(const int* __restrict__ bsum,
                                           int* __restrict__ bbase, int nb) {
    __shared__ int ls[256];
    int t = threadIdx.x;
    int v = (t < nb) ? bsum[t] : 0;
    ls[t] = v;
    __syncthreads();
    for (int off = 1; off < 256; off <<= 1) {
        int x = (t >= off) ? ls[t - off] : 0;
        __syncthreads();
        ls[t] += x;
        __syncthreads();
    }
    if (t < nb) bbase[t] = ls[t] - v;
}

__global__ __launch_bounds__(256) void scan2_both(
        const int* __restrict__ bsumA, int* __restrict__ bbaseA,
        const int* __restrict__ bsumB, int* __restrict__ bbaseB, int nb) {
    if (blockIdx.x == 0) scan2_body(bsumA, bbaseA, nb);
    else                 scan2_body(bsumB, bbaseB, nb);
}

__global__ void scan3_both(int* __restrict__ rowA, const int* __restrict__ bbaseA,
                           int* __restrict__ rowB, const int* __restrict__ bbaseB,
                           int n, int e, int nbPerSet) {
    int b = blockIdx.x;
    int* row; const int* bbase;
    if (b < nbPerSet) { row = rowA; bbase = bbaseA; }
    else              { row = rowB; bbase = bbaseB; b -= nbPerSet; }
    int i = b * 256 + threadIdx.x;
    if (i < n) row[i] += bbase[i >> 10];
    if (i == 0) row[n] = e;
}

// ---------------------------------------------------------------------------
// Fill both CSRs (grid-partitioned)
// ---------------------------------------------------------------------------
__device__ __forceinline__ void fill_body(const int* __restrict__ src,
                                          const int* __restrict__ dst,
                                          const int* __restrict__ row_start,
                                          int* __restrict__ fills,
                                          int* __restrict__ col_src, int e, int blk) {
    int i0 = (blk * 256 + threadIdx.x) * 4;
    if (i0 + 3 < e) {
        int4 s = *(const int4*)(src + i0);
        int4 d = *(const int4*)(dst + i0);
        int p;
        p = atomicAdd(&fills[d.x], 1); col_src[row_start[d.x] + p] = s.x;
        p = atomicAdd(&fills[d.y], 1); col_src[row_start[d.y] + p] = s.y;
        p = atomicAdd(&fills[d.z], 1); col_src[row_start[d.z] + p] = s.z;
        p = atomicAdd(&fills[d.w], 1); col_src[row_start[d.w] + p] = s.w;
    } else {
        for (int k = 0; k < 4 && i0 + k < e; k++) {
            int d = dst[i0 + k];
            int p = atomicAdd(&fills[d], 1);
            col_src[row_start[d] + p] = src[i0 + k];
        }
    }
}

__global__ void fill_both(const int* __restrict__ src1, const int* __restrict__ dst1,
                          const int* __restrict__ row1, int* __restrict__ fills1,
                          int* __restrict__ col1,
                          const int* __restrict__ src2, const int* __restrict__ dst2,
                          const int* __restrict__ row2, int* __restrict__ fills2,
                          int* __restrict__ col2, int e, int nbPerSet) {
    int b = blockIdx.x;
    if (b < nbPerSet) fill_body(src1, dst1, row1, fills1, col1, e, b);
    else              fill_body(src2, dst2, row2, fills2, col2, e, b - nbPerSet);
}

// ---------------------------------------------------------------------------
// GAT aggregation: one wave per destination node.
// 32 lanes cover a row via float4; wave halves process even/odd edges
// -> 16 edges (8 float4 loads x 2 rows) in flight per unrolled round.
// ---------------------------------------------------------------------------
__global__ __launch_bounds__(256) void gat_agg(const float* __restrict__ XW,
                                               const int* __restrict__ row_start,
                                               const int* __restrict__ col_src,
                                               const float* __restrict__ s_src,
                                               const float* __restrict__ s_dst,
                                               const float* __restrict__ bias,
                                               float* __restrict__ OUT, int n) {
    int v = (blockIdx.x * 256 + threadIdx.x) >> 6;
    int lane = threadIdx.x & 63;
    if (v >= n) return;
    const int h = lane >> 5;      // wave half: processes edges of that parity
    const int sl = lane & 31;     // sub-lane: covers cols [4sl, 4sl+4)

    float sdv = s_dst[v];

    // self-loop (appended unconditionally by the reference)
    float e0 = s_src[v] + sdv;
    e0 = (e0 > 0.f) ? e0 : NEG_SLOPE_C * e0;
    float p0 = __expf(e0);
    float4 xself = *(const float4*)(XW + (size_t)v * 128 + sl * 4);
    float w0 = (h == 0) ? p0 : 0.f;
    float4 acc;
    acc.x = w0 * xself.x; acc.y = w0 * xself.y;
    acc.z = w0 * xself.z; acc.w = w0 * xself.w;
    float psum_l = (lane == 0) ? p0 : 0.f;

    const int beg = row_start[v];
    const int end = row_start[v + 1];

    for (int base = beg; base < end; base += 64) {
        int m = end - base;
        if (m > 64) m = 64;
        // lane-coalesced edge ids + per-lane scalar gather + wave-parallel exp
        int u_l = (lane < m) ? col_src[base + lane] : v;
        float s = s_src[u_l] + sdv;
        s = (s > 0.f) ? s : NEG_SLOPE_C * s;
        float pe = (lane < m) ? __expf(s) : 0.f;
        psum_l += pe;

        int i = 0;
        for (; i + 16 <= m; i += 16) {
            int uu[8]; float qq[8]; float4 xx[8];
#pragma unroll
            for (int k = 0; k < 8; k++) {
                int e = i + 2 * k + h;
                uu[k] = __shfl(u_l, e);
                qq[k] = __shfl(pe, e);
            }
#pragma unroll
            for (int k = 0; k < 8; k++)
                xx[k] = *(const float4*)(XW + (size_t)uu[k] * 128 + sl * 4);
#pragma unroll
            for (int k = 0; k < 8; k++) {
                acc.x = fmaf(qq[k], xx[k].x, acc.x);
                acc.y = fmaf(qq[k], xx[k].y, acc.y);
                acc.z = fmaf(qq[k], xx[k].z, acc.z);
                acc.w = fmaf(qq[k], xx[k].w, acc.w);
            }
        }
        for (; i < m; i += 2) {
            int e = i + h;
            int ec = (e < m) ? e : 0;
            int u = __shfl(u_l, ec);
            float q = __shfl(pe, ec);
            if (e >= m) q = 0.f;
            float4 xu = *(const float4*)(XW + (size_t)u * 128 + sl * 4);
            acc.x = fmaf(q, xu.x, acc.x);
            acc.y = fmaf(q, xu.y, acc.y);
            acc.z = fmaf(q, xu.z, acc.z);
            acc.w = fmaf(q, xu.w, acc.w);
        }
    }

    // combine the two halves
    acc.x += __shfl_xor(acc.x, 32);
    acc.y += __shfl_xor(acc.y, 32);
    acc.z += __shfl_xor(acc.z, 32);
    acc.w += __shfl_xor(acc.w, 32);
    float ps = psum_l;
#pragma unroll
    for (int off = 32; off; off >>= 1) ps += __shfl_xor(ps, off);

    if (h == 0) {
        float inv = 1.0f / ps;
        float4 b4 = *(const float4*)(bias + sl * 4);
        float4 o;
        o.x = acc.x * inv + b4.x;
        o.y = acc.y * inv + b4.y;
        o.z = acc.z * inv + b4.z;
        o.w = acc.w * inv + b4.w;
        *(float4*)(OUT + (size_t)v * 128 + sl * 4) = o;
    }
}

// ---------------------------------------------------------------------------
// Final gather: out[i] = H[idx[i]]  (32 lanes x float4 per row)
// ---------------------------------------------------------------------------
__global__ __launch_bounds__(256) void gather_rows(const float* __restrict__ H,
                                                   const int* __restrict__ idx,
                                                   float* __restrict__ out, int n) {
    int t = blockIdx.x * 256 + threadIdx.x;
    int r = t >> 5;
    int l = t & 31;
    if (r >= n) return;
    int v = idx[r];
    float4 x = *(const float4*)(H + (size_t)v * 128 + l * 4);
    *(float4*)(out + (size_t)r * 128 + l * 4) = x;
}

// ---------------------------------------------------------------------------
// Launcher
// ---------------------------------------------------------------------------
extern "C" void kernel_launch(void* const* d_in, const int* in_sizes, int n_in,
                              void* d_out, int out_size, void* d_ws, size_t ws_size,
                              hipStream_t stream) {
    const float* emb   = (const float*)d_in[0];
    const float* W     = (const float*)d_in[1];
    const float* a_src = (const float*)d_in[2];
    const float* a_dst = (const float*)d_in[3];
    const float* bias  = (const float*)d_in[4];
    const int*   e1    = (const int*)d_in[5];   // [2, E]: src row then dst row
    const int*   e2    = (const int*)d_in[6];
    const int*   idx   = (const int*)d_in[7];
    float* out = (float*)d_out;

    const int n = N_NODES_C;
    const int E = N_EDGES_C;
    const int npad = 100096;                    // n rounded up, /4-aligned

    char* ws = (char*)d_ws;
    auto alloc = [&](size_t bytes) {
        char* p = ws;
        ws += (bytes + 511) & ~(size_t)511;
        return p;
    };
    float* A      = (float*)alloc((size_t)n * DIM_C * 4);   // xw of current layer
    float* B      = (float*)alloc((size_t)n * DIM_C * 4);   // layer output
    float* s_src  = (float*)alloc((size_t)n * 4);
    float* s_dst  = (float*)alloc((size_t)n * 4);
    int*   zint   = (int*)  alloc((size_t)npad * 4 * 4);    // cnt1|fills1|cnt2|fills2
    int*   rowst1 = (int*)  alloc((size_t)(n + 1) * 4);
    int*   rowst2 = (int*)  alloc((size_t)(n + 1) * 4);
    int*   bsum1  = (int*)  alloc(1024);
    int*   bsum2  = (int*)  alloc(1024);
    int*   bbase1 = (int*)  alloc(1024);
    int*   bbase2 = (int*)  alloc(1024);
    int*   col1   = (int*)  alloc((size_t)E * 4);
    int*   col2   = (int*)  alloc((size_t)E * 4);
    (void)ws_size; (void)in_sizes; (void)n_in; (void)out_size;

    int* cnt1   = zint;
    int* fills1 = zint + npad;
    int* cnt2   = zint + 2 * npad;
    int* fills2 = zint + 3 * npad;

    const int gemm_blocks  = (n + 63) / 64;                 // 1563
    const int count_blocks = (E + 1023) / 1024;             // 1563 (4 edges/thread)
    const int wave_blocks  = (n * 64 + 255) / 256;          // one wave per node
    const int scan_blocks  = (n + 1023) / 1024;             // 98 per set
    const int node_blocks  = (n + 255) / 256;               // 391 per set
    const int zero_blocks  = (npad + 255) / 256;            // int4 per thread
    const int gath_blocks  = (N_VOCAB_C * 32 + 255) / 256;

    const int* src1 = e1;           const int* dst1 = e1 + E;
    const int* src2 = e2;           const int* dst2 = e2 + E;

    // 1) zero CSR counters for both edge sets
    zero_ws<<<zero_blocks, 256, 0, stream>>>(zint, npad);
    // 2) gemm layer1 (+scalars) fused with edge counting for both sets
    fused_gemm_count<<<gemm_blocks + 2 * count_blocks, 256, 0, stream>>>(
        emb, W, a_src, a_dst, A, s_src, s_dst, dst1, dst2, cnt1, cnt2,
        n, E, gemm_blocks, count_blocks);
    // 3) scans (both sets per dispatch)
    scan1_both<<<2 * scan_blocks, 256, 0, stream>>>(cnt1, rowst1, bsum1,
                                                    cnt2, rowst2, bsum2, n, scan_blocks);
    scan2_both<<<2, 256, 0, stream>>>(bsum1, bbase1, bsum2, bbase2, scan_blocks);
    scan3_both<<<2 * node_blocks, 256, 0, stream>>>(rowst1, bbase1, rowst2, bbase2,
                                                    n, E, node_blocks);
    // 4) fill both CSRs
    fill_both<<<2 * count_blocks, 256, 0, stream>>>(src1, dst1, rowst1, fills1, col1,
                                                    src2, dst2, rowst2, fills2, col2,
                                                    E, count_blocks);
    // 5) layer 1 aggregate -> B
    gat_agg<<<wave_blocks, 256, 0, stream>>>(A, rowst1, col1, s_src, s_dst,
                                             bias, B, n);
    // 6) layer 2 gemm (B -> A) + scalars
    gemm_xw<<<gemm_blocks, 256, 0, stream>>>(B, W, a_src, a_dst, A, s_src, s_dst, n);
    // 7) layer 2 aggregate -> B
    gat_agg<<<wave_blocks, 256, 0, stream>>>(A, rowst2, col2, s_src, s_dst,
                                             bias, B, n);
    // 8) final vocab gather
    gather_rows<<<gath_blocks, 256, 0, stream>>>(B, idx, out, N_VOCAB_C);
}

// Round 5
// 748.176 us; speedup vs baseline: 1.2319x; 1.0077x over previous
//
#include <hip/hip_runtime.h>
#include <cstdint>
#include <cstddef>

#define N_NODES_C 100000
#define N_EDGES_C 1600000
#define N_VOCAB_C 50000
#define DIM_C 128
#define NEG_SLOPE_C 0.2f

typedef unsigned short u16;
typedef u16 u16x8 __attribute__((ext_vector_type(8)));
typedef __bf16 bf16x8v __attribute__((ext_vector_type(8)));
typedef float f32x4 __attribute__((ext_vector_type(4)));

__device__ __forceinline__ unsigned f2u(float x) { union { float f; unsigned u; } c; c.f = x; return c.u; }
__device__ __forceinline__ float u2f(unsigned u) { union { float f; unsigned u; } c; c.u = u; return c.f; }
__device__ __forceinline__ u16 bf_rn(float x) {
    unsigned u = f2u(x);
    return (u16)((u + 0x7FFFu + ((u >> 16) & 1u)) >> 16);
}
// split x = hi + lo, hi = truncate-to-bf16 (so hi-float is exact), lo = RN-bf16 of residual
__device__ __forceinline__ void bf_split(float x, u16& h, u16& l) {
    unsigned u = f2u(x);
    h = (u16)(u >> 16);
    float lo = x - u2f(u & 0xFFFF0000u);
    l = bf_rn(lo);
}

__device__ __forceinline__ f32x4 mfma_bf16(u16x8 a, u16x8 b, f32x4 c) {
    return __builtin_amdgcn_mfma_f32_16x16x32_bf16(
        __builtin_bit_cast(bf16x8v, a), __builtin_bit_cast(bf16x8v, b), c, 0, 0, 0);
}

// ---------------------------------------------------------------------------
// W fragment precompute (once; shared by both layers).
// Fragment f = (kstep*8 + ct)*64 + lane; lane holds col = ct*16 + (lane&15),
// k = kstep*32 + (lane>>4)*8 + e, e=0..7.  Writes Whf/Wlf in frag-linear order.
// ---------------------------------------------------------------------------
__global__ __launch_bounds__(256) void wfrag_kernel(const float* __restrict__ W,
                                                    u16* __restrict__ Whf,
                                                    u16* __restrict__ Wlf) {
    int f = blockIdx.x * 256 + threadIdx.x;
    if (f >= 2048) return;
    int ks = f >> 9, ct = (f >> 6) & 7, ln = f & 63;
    int col = ct * 16 + (ln & 15);
    int k0 = ks * 32 + (ln >> 4) * 8;
    u16x8 hv, lv;
#pragma unroll
    for (int e = 0; e < 8; e++) {
        u16 h, l;
        bf_split(W[(size_t)(k0 + e) * 128 + col], h, l);
        hv[e] = h; lv[e] = l;
    }
    *(u16x8*)(Whf + (size_t)f * 8) = hv;
    *(u16x8*)(Wlf + (size_t)f * 8) = lv;
}

// ---------------------------------------------------------------------------
// MFMA GEMM (bf16x3 ~ f32 precision): XW = X @ W, 64 rows x 128 cols / block.
// 4 waves; wave g computes rows [g*16, g*16+16) via mfma_f32_16x16x32_bf16.
// acc += Ah*Bh + Al*Bh + Ah*Bl  (drops only lo*lo ~ 2^-17 rel).
// Fused epilogue: s_src/s_dst dot products; coalesced f32 writeback via LDS.
// ---------------------------------------------------------------------------
__global__ __launch_bounds__(256) void gemm_mfma(const float* __restrict__ X,
                                                 const u16* __restrict__ Whf,
                                                 const u16* __restrict__ Wlf,
                                                 const float* __restrict__ a_src,
                                                 const float* __restrict__ a_dst,
                                                 float* __restrict__ XW,
                                                 float* __restrict__ s_src,
                                                 float* __restrict__ s_dst, int n) {
    __shared__ uint4 lds_q[6144];                 // 96 KB
    u16* Ah = (u16*)lds_q;                        // [4g][4ks][64 ln][8]  16 KB
    u16* Al = (u16*)((char*)lds_q + 16384);       // 16 KB
    u16* Bh = (u16*)((char*)lds_q + 32768);       // [4ks][8ct][64 ln][8] 32 KB
    u16* Bl = (u16*)((char*)lds_q + 65536);       // 32 KB
    float* wb = (float*)lds_q;                    // reused after compute: [64][132]

    const int t = threadIdx.x;
    const int row0 = blockIdx.x * 64;

    // stage B: linear 32KB+32KB copy (L2-resident source)
    {
        const uint4* gh = (const uint4*)Whf;
        const uint4* gl = (const uint4*)Wlf;
        uint4* lh = (uint4*)Bh;
        uint4* ll = (uint4*)Bl;
#pragma unroll
        for (int i = 0; i < 8; i++) {
            lh[t + 256 * i] = gh[t + 256 * i];
            ll[t + 256 * i] = gl[t + 256 * i];
        }
    }
    // stage A: 1024 fragment-pairs, 4 per thread; f=(g*4+ks)*64+ln
    {
        for (int i = 0; i < 4; i++) {
            int f = t + 256 * i;
            int g = f >> 8, ks = (f >> 6) & 3, ln = f & 63;
            int r = row0 + g * 16 + (ln & 15);
            int k0 = ks * 32 + (ln >> 4) * 8;
            float4 v0 = make_float4(0.f, 0.f, 0.f, 0.f), v1 = v0;
            if (r < n) {
                v0 = *(const float4*)(X + (size_t)r * 128 + k0);
                v1 = *(const float4*)(X + (size_t)r * 128 + k0 + 4);
            }
            float xe[8] = {v0.x, v0.y, v0.z, v0.w, v1.x, v1.y, v1.z, v1.w};
            u16x8 hv, lv;
#pragma unroll
            for (int e = 0; e < 8; e++) {
                u16 h, l;
                bf_split(xe[e], h, l);
                hv[e] = h; lv[e] = l;
            }
            *(u16x8*)(Ah + (size_t)f * 8) = hv;
            *(u16x8*)(Al + (size_t)f * 8) = lv;
        }
    }
    __syncthreads();

    const int g = t >> 6, l = t & 63;
    f32x4 acc[8];
#pragma unroll
    for (int ct = 0; ct < 8; ct++)
#pragma unroll
        for (int j = 0; j < 4; j++) acc[ct][j] = 0.f;

    for (int ks = 0; ks < 4; ks++) {
        u16x8 ah = *(u16x8*)(Ah + ((size_t)((g * 4 + ks) * 64 + l)) * 8);
        u16x8 al = *(u16x8*)(Al + ((size_t)((g * 4 + ks) * 64 + l)) * 8);
#pragma unroll
        for (int ct = 0; ct < 8; ct++) {
            u16x8 bh = *(u16x8*)(Bh + ((size_t)((ks * 8 + ct) * 64 + l)) * 8);
            u16x8 bl = *(u16x8*)(Bl + ((size_t)((ks * 8 + ct) * 64 + l)) * 8);
            acc[ct] = mfma_bf16(ah, bh, acc[ct]);
            acc[ct] = mfma_bf16(al, bh, acc[ct]);
            acc[ct] = mfma_bf16(ah, bl, acc[ct]);
        }
    }

    // epilogue scalars: C/D layout col = l&15, row = (l>>4)*4 + j
    const int l15 = l & 15, lg = l >> 4;
    {
        float ss[4] = {0.f, 0.f, 0.f, 0.f};
        float sd[4] = {0.f, 0.f, 0.f, 0.f};
#pragma unroll
        for (int ct = 0; ct < 8; ct++) {
            float as = a_src[ct * 16 + l15];
            float ad = a_dst[ct * 16 + l15];
#pragma unroll
            for (int j = 0; j < 4; j++) {
                ss[j] += acc[ct][j] * as;
                sd[j] += acc[ct][j] * ad;
            }
        }
#pragma unroll
        for (int off = 1; off < 16; off <<= 1)
#pragma unroll
            for (int j = 0; j < 4; j++) {
                ss[j] += __shfl_xor(ss[j], off);
                sd[j] += __shfl_xor(sd[j], off);
            }
        if (l15 == 0) {
#pragma unroll
            for (int j = 0; j < 4; j++) {
                int r = row0 + g * 16 + lg * 4 + j;
                if (r < n) { s_src[r] = ss[j]; s_dst[r] = sd[j]; }
            }
        }
    }

    // coalesced writeback via padded LDS (pitch 132 breaks bank conflicts)
    __syncthreads();   // all waves done with A/B frags before overwrite
#pragma unroll
    for (int ct = 0; ct < 8; ct++)
#pragma unroll
        for (int j = 0; j < 4; j++)
            wb[(size_t)(g * 16 + lg * 4 + j) * 132 + ct * 16 + l15] = acc[ct][j];
    // same-wave read-after-write: compiler inserts lgkmcnt wait
#pragma unroll
    for (int i = 0; i < 8; i++) {
        int idx = i * 64 + l;
        int rr = idx >> 5, c4 = idx & 31;
        int r = row0 + g * 16 + rr;
        if (r < n)
            *(float4*)(XW + (size_t)r * 128 + c4 * 4) =
                *(float4*)(wb + (size_t)(g * 16 + rr) * 132 + c4 * 4);
    }
}

// ---------------------------------------------------------------------------
// CSR build
// ---------------------------------------------------------------------------
__global__ void zero_ws(int* __restrict__ z, int n4) {
    int i = blockIdx.x * 256 + threadIdx.x;
    if (i < n4) ((int4*)z)[i] = make_int4(0, 0, 0, 0);
}

__global__ void count_both(const int* __restrict__ dst1, const int* __restrict__ dst2,
                           int* __restrict__ cnt1, int* __restrict__ cnt2,
                           int E, int cb) {
    int b = blockIdx.x;
    const int* dst; int* cnt;
    if (b < cb) { dst = dst1; cnt = cnt1; }
    else        { dst = dst2; cnt = cnt2; b -= cb; }
    int i0 = (b * 256 + threadIdx.x) * 4;
    if (i0 + 3 < E) {
        int4 d = *(const int4*)(dst + i0);
        atomicAdd(&cnt[d.x], 1);
        atomicAdd(&cnt[d.y], 1);
        atomicAdd(&cnt[d.z], 1);
        atomicAdd(&cnt[d.w], 1);
    } else {
        for (int k = 0; k < 4 && i0 + k < E; k++) atomicAdd(&cnt[dst[i0 + k]], 1);
    }
}

__device__ __forceinline__ void scan1_body(const int* __restrict__ cnt,
                                           int* __restrict__ row_start,
                                           int* __restrict__ bsum, int n, int blk) {
    __shared__ int ls[256];
    int t = threadIdx.x;
    int base = blk * 1024 + t * 4;
    int v0 = (base + 0 < n) ? cnt[base + 0] : 0;
    int v1 = (base + 1 < n) ? cnt[base + 1] : 0;
    int v2 = (base + 2 < n) ? cnt[base + 2] : 0;
    int v3 = (base + 3 < n) ? cnt[base + 3] : 0;
    int tsum = v0 + v1 + v2 + v3;
    ls[t] = tsum;
    __syncthreads();
    for (int off = 1; off < 256; off <<= 1) {
        int x = (t >= off) ? ls[t - off] : 0;
        __syncthreads();
        ls[t] += x;
        __syncthreads();
    }
    int excl = ls[t] - tsum;
    if (t == 255) bsum[blk] = ls[255];
    if (base + 0 < n) row_start[base + 0] = excl;
    if (base + 1 < n) row_start[base + 1] = excl + v0;
    if (base + 2 < n) row_start[base + 2] = excl + v0 + v1;
    if (base + 3 < n) row_start[base + 3] = excl + v0 + v1 + v2;
}

__global__ __launch_bounds__(256) void scan1_both(
        const int* __restrict__ cntA, int* __restrict__ rowA, int* __restrict__ bsumA,
        const int* __restrict__ cntB, int* __restrict__ rowB, int* __restrict__ bsumB,
        int n, int nbPerSet) {
    int b = blockIdx.x;
    if (b < nbPerSet) scan1_body(cntA, rowA, bsumA, n, b);
    else              scan1_body(cntB, rowB, bsumB, n, b - nbPerSet);
}

__device__ __forceinline__ void scan2_body(const int* __restrict__ bsum,
                                           int* __restrict__ bbase, int nb) {
    __shared__ int ls[256];
    int t = threadIdx.x;
    int v = (t < nb) ? bsum[t] : 0;
    ls[t] = v;
    __syncthreads();
    for (int off = 1; off < 256; off <<= 1) {
        int x = (t >= off) ? ls[t - off] : 0;
        __syncthreads();
        ls[t] += x;
        __syncthreads();
    }
    if (t < nb) bbase[t] = ls[t] - v;
}

__global__ __launch_bounds__(256) void scan2_both(
        const int* __restrict__ bsumA, int* __restrict__ bbaseA,
        const int* __restrict__ bsumB, int* __restrict__ bbaseB, int nb) {
    if (blockIdx.x == 0) scan2_body(bsumA, bbaseA, nb);
    else                 scan2_body(bsumB, bbaseB, nb);
}

__global__ void scan3_both(int* __restrict__ rowA, const int* __restrict__ bbaseA,
                           int* __restrict__ rowB, const int* __restrict__ bbaseB,
                           int n, int e, int nbPerSet) {
    int b = blockIdx.x;
    int* row; const int* bbase;
    if (b < nbPerSet) { row = rowA; bbase = bbaseA; }
    else              { row = rowB; bbase = bbaseB; b -= nbPerSet; }
    int i = b * 256 + threadIdx.x;
    if (i < n) row[i] += bbase[i >> 10];
    if (i == 0) row[n] = e;
}

__device__ __forceinline__ void fill_body(const int* __restrict__ src,
                                          const int* __restrict__ dst,
                                          const int* __restrict__ row_start,
                                          int* __restrict__ fills,
                                          int* __restrict__ col_src, int e, int blk) {
    int i0 = (blk * 256 + threadIdx.x) * 4;
    if (i0 + 3 < e) {
        int4 s = *(const int4*)(src + i0);
        int4 d = *(const int4*)(dst + i0);
        int p;
        p = atomicAdd(&fills[d.x], 1); col_src[row_start[d.x] + p] = s.x;
        p = atomicAdd(&fills[d.y], 1); col_src[row_start[d.y] + p] = s.y;
        p = atomicAdd(&fills[d.z], 1); col_src[row_start[d.z] + p] = s.z;
        p = atomicAdd(&fills[d.w], 1); col_src[row_start[d.w] + p] = s.w;
    } else {
        for (int k = 0; k < 4 && i0 + k < e; k++) {
            int d = dst[i0 + k];
            int p = atomicAdd(&fills[d], 1);
            col_src[row_start[d] + p] = src[i0 + k];
        }
    }
}

__global__ void fill_both(const int* __restrict__ src1, const int* __restrict__ dst1,
                          const int* __restrict__ row1, int* __restrict__ fills1,
                          int* __restrict__ col1,
                          const int* __restrict__ src2, const int* __restrict__ dst2,
                          const int* __restrict__ row2, int* __restrict__ fills2,
                          int* __restrict__ col2, int e, int nbPerSet) {
    int b = blockIdx.x;
    if (b < nbPerSet) fill_body(src1, dst1, row1, fills1, col1, e, b);
    else              fill_body(src2, dst2, row2, fills2, col2, e, b - nbPerSet);
}

// ---------------------------------------------------------------------------
// GAT aggregation: one wave per destination node (as R2; 16 edges in flight)
// ---------------------------------------------------------------------------
__global__ __launch_bounds__(256) void gat_agg(const float* __restrict__ XW,
                                               const int* __restrict__ row_start,
                                               const int* __restrict__ col_src,
                                               const float* __restrict__ s_src,
                                               const float* __restrict__ s_dst,
                                               const float* __restrict__ bias,
                                               float* __restrict__ OUT, int n) {
    int v = (blockIdx.x * 256 + threadIdx.x) >> 6;
    int lane = threadIdx.x & 63;
    if (v >= n) return;
    const int h = lane >> 5;
    const int sl = lane & 31;

    float sdv = s_dst[v];

    float e0 = s_src[v] + sdv;
    e0 = (e0 > 0.f) ? e0 : NEG_SLOPE_C * e0;
    float p0 = __expf(e0);
    float4 xself = *(const float4*)(XW + (size_t)v * 128 + sl * 4);
    float w0 = (h == 0) ? p0 : 0.f;
    float4 acc;
    acc.x = w0 * xself.x; acc.y = w0 * xself.y;
    acc.z = w0 * xself.z; acc.w = w0 * xself.w;
    float psum_l = (lane == 0) ? p0 : 0.f;

    const int beg = row_start[v];
    const int end = row_start[v + 1];

    for (int base = beg; base < end; base += 64) {
        int m = end - base;
        if (m > 64) m = 64;
        int u_l = (lane < m) ? col_src[base + lane] : v;
        float s = s_src[u_l] + sdv;
        s = (s > 0.f) ? s : NEG_SLOPE_C * s;
        float pe = (lane < m) ? __expf(s) : 0.f;
        psum_l += pe;

        int i = 0;
        for (; i + 16 <= m; i += 16) {
            int uu[8]; float qq[8]; float4 xx[8];
#pragma unroll
            for (int k = 0; k < 8; k++) {
                int e = i + 2 * k + h;
                uu[k] = __shfl(u_l, e);
                qq[k] = __shfl(pe, e);
            }
#pragma unroll
            for (int k = 0; k < 8; k++)
                xx[k] = *(const float4*)(XW + (size_t)uu[k] * 128 + sl * 4);
#pragma unroll
            for (int k = 0; k < 8; k++) {
                acc.x = fmaf(qq[k], xx[k].x, acc.x);
                acc.y = fmaf(qq[k], xx[k].y, acc.y);
                acc.z = fmaf(qq[k], xx[k].z, acc.z);
                acc.w = fmaf(qq[k], xx[k].w, acc.w);
            }
        }
        for (; i < m; i += 2) {
            int e = i + h;
            int ec = (e < m) ? e : 0;
            int u = __shfl(u_l, ec);
            float q = __shfl(pe, ec);
            if (e >= m) q = 0.f;
            float4 xu = *(const float4*)(XW + (size_t)u * 128 + sl * 4);
            acc.x = fmaf(q, xu.x, acc.x);
            acc.y = fmaf(q, xu.y, acc.y);
            acc.z = fmaf(q, xu.z, acc.z);
            acc.w = fmaf(q, xu.w, acc.w);
        }
    }

    acc.x += __shfl_xor(acc.x, 32);
    acc.y += __shfl_xor(acc.y, 32);
    acc.z += __shfl_xor(acc.z, 32);
    acc.w += __shfl_xor(acc.w, 32);
    float ps = psum_l;
#pragma unroll
    for (int off = 32; off; off >>= 1) ps += __shfl_xor(ps, off);

    if (h == 0) {
        float inv = 1.0f / ps;
        float4 b4 = *(const float4*)(bias + sl * 4);
        float4 o;
        o.x = acc.x * inv + b4.x;
        o.y = acc.y * inv + b4.y;
        o.z = acc.z * inv + b4.z;
        o.w = acc.w * inv + b4.w;
        *(float4*)(OUT + (size_t)v * 128 + sl * 4) = o;
    }
}

// ---------------------------------------------------------------------------
// Final gather
// ---------------------------------------------------------------------------
__global__ __launch_bounds__(256) void gather_rows(const float* __restrict__ H,
                                                   const int* __restrict__ idx,
                                                   float* __restrict__ out, int n) {
    int t = blockIdx.x * 256 + threadIdx.x;
    int r = t >> 5;
    int l = t & 31;
    if (r >= n) return;
    int v = idx[r];
    float4 x = *(const float4*)(H + (size_t)v * 128 + l * 4);
    *(float4*)(out + (size_t)r * 128 + l * 4) = x;
}

// ---------------------------------------------------------------------------
// Launcher
// ---------------------------------------------------------------------------
extern "C" void kernel_launch(void* const* d_in, const int* in_sizes, int n_in,
                              void* d_out, int out_size, void* d_ws, size_t ws_size,
                              hipStream_t stream) {
    const float* emb   = (const float*)d_in[0];
    const float* W     = (const float*)d_in[1];
    const float* a_src = (const float*)d_in[2];
    const float* a_dst = (const float*)d_in[3];
    const float* bias  = (const float*)d_in[4];
    const int*   e1    = (const int*)d_in[5];
    const int*   e2    = (const int*)d_in[6];
    const int*   idx   = (const int*)d_in[7];
    float* out = (float*)d_out;

    const int n = N_NODES_C;
    const int E = N_EDGES_C;
    const int npad = 100096;

    char* ws = (char*)d_ws;
    auto alloc = [&](size_t bytes) {
        char* p = ws;
        ws += (bytes + 511) & ~(size_t)511;
        return p;
    };
    float* A      = (float*)alloc((size_t)n * DIM_C * 4);
    float* B      = (float*)alloc((size_t)n * DIM_C * 4);
    float* s_src  = (float*)alloc((size_t)n * 4);
    float* s_dst  = (float*)alloc((size_t)n * 4);
    int*   zint   = (int*)  alloc((size_t)npad * 4 * 4);    // cnt1|fills1|cnt2|fills2
    int*   rowst1 = (int*)  alloc((size_t)(n + 1) * 4);
    int*   rowst2 = (int*)  alloc((size_t)(n + 1) * 4);
    int*   bsum1  = (int*)  alloc(1024);
    int*   bsum2  = (int*)  alloc(1024);
    int*   bbase1 = (int*)  alloc(1024);
    int*   bbase2 = (int*)  alloc(1024);
    int*   col1   = (int*)  alloc((size_t)E * 4);
    int*   col2   = (int*)  alloc((size_t)E * 4);
    u16*   Whf    = (u16*)  alloc(32768);
    u16*   Wlf    = (u16*)  alloc(32768);
    (void)ws_size; (void)in_sizes; (void)n_in; (void)out_size;

    int* cnt1   = zint;
    int* fills1 = zint + npad;
    int* cnt2   = zint + 2 * npad;
    int* fills2 = zint + 3 * npad;

    const int gemm_blocks  = (n + 63) / 64;
    const int count_blocks = (E + 1023) / 1024;
    const int wave_blocks  = (n * 64 + 255) / 256;
    const int scan_blocks  = (n + 1023) / 1024;
    const int node_blocks  = (n + 255) / 256;
    const int zero_blocks  = (npad + 255) / 256;
    const int gath_blocks  = (N_VOCAB_C * 32 + 255) / 256;

    const int* src1 = e1;  const int* dst1 = e1 + E;
    const int* src2 = e2;  const int* dst2 = e2 + E;

    // W fragments (once, reused by both layers)
    wfrag_kernel<<<8, 256, 0, stream>>>(W, Whf, Wlf);
    // CSR build for both edge sets
    zero_ws<<<zero_blocks, 256, 0, stream>>>(zint, npad);
    count_both<<<2 * count_blocks, 256, 0, stream>>>(dst1, dst2, cnt1, cnt2, E,
                                                     count_blocks);
    scan1_both<<<2 * scan_blocks, 256, 0, stream>>>(cnt1, rowst1, bsum1,
                                                    cnt2, rowst2, bsum2, n, scan_blocks);
    scan2_both<<<2, 256, 0, stream>>>(bsum1, bbase1, bsum2, bbase2, scan_blocks);
    scan3_both<<<2 * node_blocks, 256, 0, stream>>>(rowst1, bbase1, rowst2, bbase2,
                                                    n, E, node_blocks);
    fill_both<<<2 * count_blocks, 256, 0, stream>>>(src1, dst1, rowst1, fills1, col1,
                                                    src2, dst2, rowst2, fills2, col2,
                                                    E, count_blocks);
    // layer 1
    gemm_mfma<<<gemm_blocks, 256, 0, stream>>>(emb, Whf, Wlf, a_src, a_dst,
                                               A, s_src, s_dst, n);
    gat_agg<<<wave_blocks, 256, 0, stream>>>(A, rowst1, col1, s_src, s_dst,
                                             bias, B, n);
    // layer 2 (same params)
    gemm_mfma<<<gemm_blocks, 256, 0, stream>>>(B, Whf, Wlf, a_src, a_dst,
                                               A, s_src, s_dst, n);
    gat_agg<<<wave_blocks, 256, 0, stream>>>(A, rowst2, col2, s_src, s_dst,
                                             bias, B, n);
    // final vocab gather
    gather_rows<<<gath_blocks, 256, 0, stream>>>(B, idx, out, N_VOCAB_C);
}